// Round 3
// baseline (217.348 us; speedup 1.0000x reference)
//
#include <hip/hip_runtime.h>

#define KK 32
#define HH 6
#define OO 31
#define KT 16
#define EPS 1e-6f

#define KHO (KK * HH * OO)          // 5952 dwords of W
#define MIX_DW (256 * OO)           // 7936 dwords: per-block mix / epilogue region

// One thread per point. cd/gw staged to registers as float4 bursts (R2 win:
// MSHR-merge -> compulsory HBM traffic). W staged to LDS once per block;
// inner-loop W reads are wave-uniform ds_read_b128 broadcasts (no SMEM/SGPR
// chunk stalls). Epilogue: mix -> LDS (stride-31 write, 2-way alias = free),
// then fully-coalesced float4 mlp*mix -> out over the block's contiguous range.
__global__ __launch_bounds__(256, 4) void hermite_fused_kernel(
    const float* __restrict__ mlp,     // [P, OO]
    const float* __restrict__ cd,      // [P, KK, 2]
    const float* __restrict__ sigmas,  // [KK]
    const float* __restrict__ gw,      // [P, KK]
    const float* __restrict__ W,       // [KK, HH, OO]
    float* __restrict__ out,           // [P, OO]
    int P)
{
    __shared__ float smem[MIX_DW];     // W lives in [0, KHO) during k-loop
    __shared__ float s_i2[KK];
    __shared__ float s_i4[KK];

    const int tid = threadIdx.x;
    if (tid < KK) {
        float s = sigmas[tid];
        s_i2[tid] = 1.0f / (s * s + EPS);
        s_i4[tid] = 1.0f / (s * s * s * s + EPS);
    }

    // Stage W -> LDS, coalesced float4 (5952 dwords = 1488 float4).
    {
        const float4* __restrict__ Wv = (const float4*)W;
        float4* sWv = (float4*)smem;
        for (int j = tid; j < KHO / 4; j += 256) {
            sWv[j] = Wv[j];
        }
    }
    __syncthreads();

    const int p = blockIdx.x * blockDim.x + tid;

    float acc[OO];
#pragma unroll
    for (int o = 0; o < OO; ++o) acc[o] = 0.0f;

    if (p < P) {
        const float4* __restrict__ cdv = (const float4*)(cd + (size_t)p * (KK * 2));
        const float4* __restrict__ gwv = (const float4*)(gw + (size_t)p * KK);

#pragma unroll 1
        for (int kt = 0; kt < KK / KT; ++kt) {
            float cf[KT * 2];
            float gf[KT];
#pragma unroll
            for (int i = 0; i < KT / 2; ++i) {
                float4 t = cdv[kt * (KT / 2) + i];
                cf[4 * i + 0] = t.x;
                cf[4 * i + 1] = t.y;
                cf[4 * i + 2] = t.z;
                cf[4 * i + 3] = t.w;
            }
#pragma unroll
            for (int i = 0; i < KT / 4; ++i) {
                float4 t = gwv[kt * (KT / 4) + i];
                gf[4 * i + 0] = t.x;
                gf[4 * i + 1] = t.y;
                gf[4 * i + 2] = t.z;
                gf[4 * i + 3] = t.w;
            }

#pragma unroll
            for (int j = 0; j < KT; ++j) {
                const int k = kt * KT + j;
                float dx = cf[2 * j + 0];
                float dy = cf[2 * j + 1];
                float g  = gf[j];
                float i2 = s_i2[k];
                float i4 = s_i4[k];

                float t2 = g * i2;               // g / s2
                float t4 = g * i4;               // g / s4
                float dxt4 = dx * t4;
                float dyt4 = dy * t4;

                float d0 = g;                    // (0,0)
                float d1 = -dy * t2;             // (0,1)
                float d2 = -dx * t2;             // (1,0)
                float d3 = fmaf(dy, dyt4, -t2);  // (0,2)
                float d4 = dx * dyt4;            // (1,1)
                float d5 = fmaf(dx, dxt4, -t2);  // (2,0)

                const float* Wk = &smem[k * (HH * OO)]; // wave-uniform -> broadcast
#pragma unroll
                for (int o = 0; o < OO; ++o) {
                    float a = acc[o];
                    a = fmaf(d0, Wk[0 * OO + o], a);
                    a = fmaf(d1, Wk[1 * OO + o], a);
                    a = fmaf(d2, Wk[2 * OO + o], a);
                    a = fmaf(d3, Wk[3 * OO + o], a);
                    a = fmaf(d4, Wk[4 * OO + o], a);
                    a = fmaf(d5, Wk[5 * OO + o], a);
                    acc[o] = a;
                }
            }
        }
    }

    // Reuse smem for the mix tile (all waves are done reading W).
    __syncthreads();
#pragma unroll
    for (int o = 0; o < OO; ++o) {
        smem[tid * OO + o] = acc[o];   // lanes t, t+32 alias banks: 2-way = free
    }
    __syncthreads();

    // Coalesced epilogue: block's output range is MIX_DW contiguous dwords,
    // flat dword d maps 1:1 to smem[d]. Pure float4 traffic.
    {
        const size_t blk_dw = (size_t)blockIdx.x * MIX_DW;
        const float4* __restrict__ mlpv = (const float4*)(mlp + blk_dw);
        float4* __restrict__ outv = (float4*)(out + blk_dw);
        const float4* mixv = (const float4*)smem;
        const int nf4 = MIX_DW / 4;            // 1984
        const size_t total_dw = (size_t)P * OO;
        for (int j = tid; j < nf4; j += 256) {
            if (blk_dw + 4 * j + 3 < total_dw) {
                float4 m = mlpv[j];
                float4 x = mixv[j];
                float4 r;
                r.x = m.x * x.x;
                r.y = m.y * x.y;
                r.z = m.z * x.z;
                r.w = m.w * x.w;
                outv[j] = r;
            }
        }
    }
}

extern "C" void kernel_launch(void* const* d_in, const int* in_sizes, int n_in,
                              void* d_out, int out_size, void* d_ws, size_t ws_size,
                              hipStream_t stream) {
    const float* mlp    = (const float*)d_in[0]; // [B,N,O]
    const float* cd     = (const float*)d_in[1]; // [B,N,K,2]
    const float* sigmas = (const float*)d_in[2]; // [K]
    const float* gw     = (const float*)d_in[3]; // [B,N,K]
    const float* W      = (const float*)d_in[4]; // [K,H,O]
    float* out          = (float*)d_out;

    const int P = in_sizes[3] / KK; // B*N
    const int block = 256;
    const int grid = (P + block - 1) / block;

    hermite_fused_kernel<<<grid, block, 0, stream>>>(mlp, cd, sigmas, gw, W, out, P);
}

// Round 4
// 211.216 us; speedup vs baseline: 1.0290x; 1.0290x over previous
//
#include <hip/hip_runtime.h>

#define KK 32
#define HH 6
#define OO 31
#define OP 32                      // padded O stride in LDS
#define KT 8                       // k-tile for cd/gw register bursts
#define EPS 1e-6f

#define W_DW (KK * HH * OP)        // 6144 dwords padded W
#define PTS_BLK 512                // points per block (256 threads x M=2)
#define MIX_DW (PTS_BLK * OO)      // 15872 dwords mix region (reuses W region)

// M=2 points/thread. W staged to LDS padded [K][H][32] (16B-aligned rows ->
// ds_read_b128), each b128 feeds 12 FMAs (4 outs x ... x 2 points) -> LDS-pipe
// inst count cut ~4x vs R3 (alignment 2x, M=2 2x). cd/gw streamed as float4
// bursts (full-sector consumption -> compulsory HBM). Epilogue: mix -> LDS
// (conflict-free (o - lane) mod 32 banks), then coalesced float4 mlp*mix.
__global__ __launch_bounds__(256, 2) void hermite_fused_kernel(
    const float* __restrict__ mlp,     // [P, OO]
    const float* __restrict__ cd,      // [P, KK, 2]
    const float* __restrict__ sigmas,  // [KK]
    const float* __restrict__ gw,      // [P, KK]
    const float* __restrict__ W,       // [KK, HH, OO]
    float* __restrict__ out,           // [P, OO]
    int P)
{
    __shared__ float smem[MIX_DW];     // [0,W_DW) = padded W during k-loop
    __shared__ float s_i2[KK];
    __shared__ float s_i4[KK];

    const int tid = threadIdx.x;
    if (tid < KK) {
        float s = sigmas[tid];
        s_i2[tid] = 1.0f / (s * s + EPS);
        s_i4[tid] = 1.0f / (s * s * s * s + EPS);
    }

    // Stage W -> LDS, padded to [K][H][32], pad col = 0.
    for (int j = tid; j < W_DW; j += 256) {
        int k = j / (HH * OP);
        int r = j - k * (HH * OP);
        int h = r >> 5;
        int o = r & 31;
        smem[j] = (o < OO) ? W[k * (HH * OO) + h * OO + o] : 0.0f;
    }
    __syncthreads();

    const int pA = blockIdx.x * PTS_BLK + tid;       // point A
    // point B = pA + 256
    const float4* __restrict__ cdA = (const float4*)(cd + (size_t)pA * (KK * 2));
    const float4* __restrict__ cdB = cdA + (256 * KK * 2) / 4;
    const float4* __restrict__ gwA = (const float4*)(gw + (size_t)pA * KK);
    const float4* __restrict__ gwB = gwA + (256 * KK) / 4;

    float accA[OP], accB[OP];
#pragma unroll
    for (int o = 0; o < OP; ++o) { accA[o] = 0.0f; accB[o] = 0.0f; }

#pragma unroll 1
    for (int kt = 0; kt < KK / KT; ++kt) {
        float cA[KT * 2], cB[KT * 2], gA[KT], gB[KT];
#pragma unroll
        for (int i = 0; i < KT / 2; ++i) {          // 4 float4 each: one full 64B sector
            float4 t = cdA[kt * (KT / 2) + i];
            cA[4 * i + 0] = t.x; cA[4 * i + 1] = t.y; cA[4 * i + 2] = t.z; cA[4 * i + 3] = t.w;
        }
#pragma unroll
        for (int i = 0; i < KT / 2; ++i) {
            float4 t = cdB[kt * (KT / 2) + i];
            cB[4 * i + 0] = t.x; cB[4 * i + 1] = t.y; cB[4 * i + 2] = t.z; cB[4 * i + 3] = t.w;
        }
#pragma unroll
        for (int i = 0; i < KT / 4; ++i) {
            float4 t = gwA[kt * (KT / 4) + i];
            gA[4 * i + 0] = t.x; gA[4 * i + 1] = t.y; gA[4 * i + 2] = t.z; gA[4 * i + 3] = t.w;
        }
#pragma unroll
        for (int i = 0; i < KT / 4; ++i) {
            float4 t = gwB[kt * (KT / 4) + i];
            gB[4 * i + 0] = t.x; gB[4 * i + 1] = t.y; gB[4 * i + 2] = t.z; gB[4 * i + 3] = t.w;
        }

#pragma unroll
        for (int j = 0; j < KT; ++j) {
            const int k = kt * KT + j;
            float i2 = s_i2[k];
            float i4 = s_i4[k];

            float dxA = cA[2 * j], dyA = cA[2 * j + 1], ga = gA[j];
            float t2A = ga * i2, t4A = ga * i4;
            float dxt4A = dxA * t4A, dyt4A = dyA * t4A;
            float d0A = ga;
            float d1A = -dyA * t2A;
            float d2A = -dxA * t2A;
            float d3A = fmaf(dyA, dyt4A, -t2A);
            float d4A = dxA * dyt4A;
            float d5A = fmaf(dxA, dxt4A, -t2A);

            float dxB = cB[2 * j], dyB = cB[2 * j + 1], gb = gB[j];
            float t2B = gb * i2, t4B = gb * i4;
            float dxt4B = dxB * t4B, dyt4B = dyB * t4B;
            float d0B = gb;
            float d1B = -dyB * t2B;
            float d2B = -dxB * t2B;
            float d3B = fmaf(dyB, dyt4B, -t2B);
            float d4B = dxB * dyt4B;
            float d5B = fmaf(dxB, dxt4B, -t2B);

            const float4* Wk = (const float4*)&smem[k * (HH * OP)]; // 16B-aligned
#pragma unroll
            for (int oq = 0; oq < OP / 4; ++oq) {
                float4 w0 = Wk[0 * (OP / 4) + oq];
                float4 w1 = Wk[1 * (OP / 4) + oq];
                float4 w2 = Wk[2 * (OP / 4) + oq];
                float4 w3 = Wk[3 * (OP / 4) + oq];
                float4 w4 = Wk[4 * (OP / 4) + oq];
                float4 w5 = Wk[5 * (OP / 4) + oq];
#define HFMA(ACC, D0, D1, D2, D3, D4, D5, C)            \
                {   float a = ACC;                      \
                    a = fmaf(D0, w0.C, a);              \
                    a = fmaf(D1, w1.C, a);              \
                    a = fmaf(D2, w2.C, a);              \
                    a = fmaf(D3, w3.C, a);              \
                    a = fmaf(D4, w4.C, a);              \
                    a = fmaf(D5, w5.C, a);              \
                    ACC = a; }
                HFMA(accA[4 * oq + 0], d0A, d1A, d2A, d3A, d4A, d5A, x)
                HFMA(accA[4 * oq + 1], d0A, d1A, d2A, d3A, d4A, d5A, y)
                HFMA(accA[4 * oq + 2], d0A, d1A, d2A, d3A, d4A, d5A, z)
                HFMA(accA[4 * oq + 3], d0A, d1A, d2A, d3A, d4A, d5A, w)
                HFMA(accB[4 * oq + 0], d0B, d1B, d2B, d3B, d4B, d5B, x)
                HFMA(accB[4 * oq + 1], d0B, d1B, d2B, d3B, d4B, d5B, y)
                HFMA(accB[4 * oq + 2], d0B, d1B, d2B, d3B, d4B, d5B, z)
                HFMA(accB[4 * oq + 3], d0B, d1B, d2B, d3B, d4B, d5B, w)
#undef HFMA
            }
        }
    }

    // Reuse smem as the mix tile.
    __syncthreads();
#pragma unroll
    for (int o = 0; o < OO; ++o) {
        smem[tid * OO + o] = accA[o];           // banks (o - lane) mod 32: conflict-free
        smem[(tid + 256) * OO + o] = accB[o];
    }
    __syncthreads();

    // Coalesced epilogue: block's output range = MIX_DW contiguous dwords,
    // flat dword d maps 1:1 to smem[d]. P = 512*512 exactly -> no bounds check.
    {
        const size_t blk_dw = (size_t)blockIdx.x * MIX_DW;
        const float4* __restrict__ mlpv = (const float4*)(mlp + blk_dw);
        float4* __restrict__ outv = (float4*)(out + blk_dw);
        const float4* mixv = (const float4*)smem;
#pragma unroll 4
        for (int j = tid; j < MIX_DW / 4; j += 256) {
            float4 m = mlpv[j];
            float4 x = mixv[j];
            float4 r;
            r.x = m.x * x.x;
            r.y = m.y * x.y;
            r.z = m.z * x.z;
            r.w = m.w * x.w;
            outv[j] = r;
        }
    }
}

extern "C" void kernel_launch(void* const* d_in, const int* in_sizes, int n_in,
                              void* d_out, int out_size, void* d_ws, size_t ws_size,
                              hipStream_t stream) {
    const float* mlp    = (const float*)d_in[0]; // [B,N,O]
    const float* cd     = (const float*)d_in[1]; // [B,N,K,2]
    const float* sigmas = (const float*)d_in[2]; // [K]
    const float* gw     = (const float*)d_in[3]; // [B,N,K]
    const float* W      = (const float*)d_in[4]; // [K,H,O]
    float* out          = (float*)d_out;

    const int P = in_sizes[3] / KK; // B*N = 262144
    const int grid = P / PTS_BLK;   // 512 blocks (P divides exactly)

    hermite_fused_kernel<<<grid, 256, 0, stream>>>(mlp, cd, sigmas, gw, W, out, P);
}